// Round 6
// baseline (97.028 us; speedup 1.0000x reference)
//
#include <hip/hip_runtime.h>
#include <math.h>

// Problem constants (reference: B=2048, CI=32, CO=32, A=16, ITER_NUM=5)
constexpr int CI = 32;
constexpr int CO = 32;
constexpr float INV_N   = 1.0f / 65536.0f;
constexpr float INV_NM1 = 1.0f / 65535.0f;

constexpr int NCHUNK = 32;                 // chunks per capsule (grid = 32*32)
constexpr int PART_STRIDE = 272;           // 4 subs * 68 (64 prods + 4 sums)

// d_ws float layout (no zero-init required):
//   WS_PART: [CI][NCHUNK][272] per-block partials
//   WS_W:    [CI][256] whitening matrices, then [CI][16] raw sums S
constexpr int WS_PART = 0;
constexpr int WS_W    = CI * NCHUNK * PART_STRIDE;   // 278528
constexpr int WS_S    = WS_W + CI * 256;

using f32x4 = __attribute__((ext_vector_type(4))) float;

// Broadcast float from lane (quadbase+q) to all lanes of the quad (VALU DPP).
template <int CTRL>
__device__ __forceinline__ float quad_bcast(float v) {
    return __int_as_float(
        __builtin_amdgcn_mov_dpp(__float_as_int(v), CTRL, 0xf, 0xf, true));
}

// ---------------------------------------------------------------------------
// Kernel 1: per-capsule raw sums S[a] = sum x_a, P[a][b] = sum x_a x_b.
// Grid: 32 ci * 32 chunks = 1024 blocks of 256 threads.
// DENSE loads: lane l reads exactly bytes l*16 of a contiguous 1KB wave chunk
// (= quarter (l&3) of vector (l>>2)); the full 16-float vector is rebuilt with
// 16 DPP quad-perm broadcasts. No redundant / strided global traffic.
// Lane accumulates rows sub*4..sub*4+3 (its own quarter) x all 16 columns.
// ---------------------------------------------------------------------------
__global__ __launch_bounds__(256) void k_stats(const float* __restrict__ x,
                                               float* __restrict__ ws) {
    const int ci    = blockIdx.x & 31;
    const int chunk = blockIdx.x >> 5;          // 0..31
    const int tid   = threadIdx.x;
    const int lane  = tid & 63;
    const int wv    = tid >> 6;
    const int sub   = lane & 3;                 // quarter / row-group selector

    float acc[4][16];
    float sacc[4];
#pragma unroll
    for (int i = 0; i < 4; ++i) {
        sacc[i] = 0.0f;
#pragma unroll
        for (int b2 = 0; b2 < 16; ++b2) acc[i][b2] = 0.0f;
    }

    // Wave's first vector slot: n0 = chunk*2048 + it*64 + wv*16.
    // b = n0>>5 = chunk*64 + it*2 + (wv>>1); co0 = (wv&1)*16.
    // Lane float index = (b*1024 + ci*32 + co0)*16 + lane*4; iter stride =
    // 2 batches = 32768 floats (128 KB), constant.
    const float* p = x +
        (((size_t)(chunk * 64 + (wv >> 1)) * 1024 + ci * 32 + (wv & 1) * 16) * 16
         + lane * 4);

    for (int it = 0; it < 32; ++it, p += 32768) {
        const float4 f = *reinterpret_cast<const float4*>(p);
        const float ow[4] = {f.x, f.y, f.z, f.w};   // own quarter (rows)

        float v[16];                                 // full vector via DPP
#pragma unroll
        for (int j = 0; j < 4; ++j) {
            v[0  + j] = quad_bcast<0x00>(ow[j]);
            v[4  + j] = quad_bcast<0x55>(ow[j]);
            v[8  + j] = quad_bcast<0xAA>(ow[j]);
            v[12 + j] = quad_bcast<0xFF>(ow[j]);
        }

#pragma unroll
        for (int i = 0; i < 4; ++i) {
            sacc[i] += ow[i];
#pragma unroll
            for (int b2 = 0; b2 < 16; ++b2) acc[i][b2] += ow[i] * v[b2];
        }
    }

    // Butterfly-reduce across the 16 quads of the wave (lanes with same sub).
#pragma unroll
    for (int m = 4; m < 64; m <<= 1) {
#pragma unroll
        for (int i = 0; i < 4; ++i) {
            sacc[i] += __shfl_xor(sacc[i], m, 64);
#pragma unroll
            for (int b2 = 0; b2 < 16; ++b2)
                acc[i][b2] += __shfl_xor(acc[i][b2], m, 64);
        }
    }

    // Cross-wave reduce in LDS: lanes 0..3 of each wave hold wave totals.
    __shared__ float red[4][272];
    if (lane < 4) {
#pragma unroll
        for (int i = 0; i < 4; ++i) {
#pragma unroll
            for (int b2 = 0; b2 < 16; ++b2)
                red[wv][sub * 68 + i * 16 + b2] = acc[i][b2];
            red[wv][sub * 68 + 64 + i] = sacc[i];
        }
    }
    __syncthreads();
    float* slot = ws + WS_PART + (ci * NCHUNK + chunk) * PART_STRIDE;
    for (int e = tid; e < 272; e += 256) {
        slot[e] = red[0][e] + red[1][e] + red[2][e] + red[3][e];
    }
}

// ---------------------------------------------------------------------------
// Kernel 2: reduce chunk partials, then Newton-Schulz inverse sqrt of the
// 16x16 covariance. 32 blocks (one per ci) of 256 threads.
// ---------------------------------------------------------------------------
__global__ __launch_bounds__(256) void k_ns(float* __restrict__ ws) {
    const int ci  = blockIdx.x;
    const int tid = threadIdx.x;
    const int r = tid >> 4, c = tid & 15;

    __shared__ float red2[272];
    __shared__ float sig[16][17];
    __shared__ float pm[16][17];
    __shared__ float t1[16][17];
    __shared__ float t2[16][17];
    __shared__ float trace_s;

    const float* base = ws + WS_PART + (size_t)ci * NCHUNK * PART_STRIDE;
    for (int e = tid; e < 272; e += 256) {
        float s = 0.0f;
#pragma unroll
        for (int ch = 0; ch < NCHUNK; ++ch)
            s += base[ch * PART_STRIDE + e];
        red2[e] = s;
    }
    __syncthreads();

    // sigma[r][c] = (P_rc - S_r*S_c/N) / (N-1)
    const float P_rc = red2[(r >> 2) * 68 + ((r & 3) << 4) + c];
    const float S_r  = red2[(r >> 2) * 68 + 64 + (r & 3)];
    const float S_c  = red2[(c >> 2) * 68 + 64 + (c & 3)];
    sig[r][c] = (P_rc - S_r * S_c * INV_N) * INV_NM1;
    __syncthreads();

    if (tid == 0) {
        float tr = 0.0f;
        for (int i = 0; i < 16; ++i) tr += sig[i][i];
        trace_s = tr;
    }
    __syncthreads();
    const float tr = trace_s;

    sig[r][c] = sig[r][c] / tr;                 // sigma_n
    pm[r][c]  = (r == c) ? 1.0f : 0.0f;
    __syncthreads();

    for (int it = 0; it < 5; ++it) {
        float a = 0.0f;
        for (int k = 0; k < 16; ++k) a += pm[r][k] * pm[k][c];
        t1[r][c] = a;
        __syncthreads();
        float b2 = 0.0f;
        for (int k = 0; k < 16; ++k) b2 += t1[r][k] * pm[k][c];
        t2[r][c] = b2;
        __syncthreads();
        float d = 0.0f;
        for (int k = 0; k < 16; ++k) d += t2[r][k] * sig[k][c];
        const float np = 0.5f * (3.0f * pm[r][c] - d);
        __syncthreads();
        pm[r][c] = np;
        __syncthreads();
    }

    ws[WS_W + ci * 256 + r * 16 + c] = pm[r][c] / sqrtf(tr);
    if (tid < 16)
        ws[WS_S + ci * 16 + tid] = red2[(tid >> 2) * 68 + 64 + (tid & 3)];
}

// ---------------------------------------------------------------------------
// Kernel 3: out = ((x - m) @ W) * gamma + beta, folded as x @ (W*g) + c0.
// Same dense-load + DPP-broadcast structure as k_stats; lane's own 16B slot
// is exactly the 4 output columns it computes -> dense dwordx4 store (nt).
// ---------------------------------------------------------------------------
__global__ __launch_bounds__(256) void k_apply(const float* __restrict__ x,
                                               const float* __restrict__ gamma,
                                               const float* __restrict__ beta,
                                               const float* __restrict__ ws,
                                               float* __restrict__ out) {
    const int ci    = blockIdx.x & 31;
    const int chunk = blockIdx.x >> 5;          // 0..31
    const int tid   = threadIdx.x;
    const int lane  = tid & 63;
    const int wv    = tid >> 6;
    const int sub   = lane & 3;
    const int b0    = sub * 4;                  // output column group

    const float* W = ws + WS_W + ci * 256;
    const float* S = ws + WS_S + ci * 16;

    float g[4], c0[4];
#pragma unroll
    for (int i = 0; i < 4; ++i) g[i] = gamma[ci * 16 + b0 + i];

    float wg[16][4];
    float bias[4] = {0.0f, 0.0f, 0.0f, 0.0f};
#pragma unroll
    for (int a = 0; a < 16; ++a) {
        const float4 wr = *reinterpret_cast<const float4*>(W + a * 16 + b0);
        const float m = S[a] * INV_N;
        wg[a][0] = wr.x * g[0]; wg[a][1] = wr.y * g[1];
        wg[a][2] = wr.z * g[2]; wg[a][3] = wr.w * g[3];
        bias[0] += m * wr.x; bias[1] += m * wr.y;
        bias[2] += m * wr.z; bias[3] += m * wr.w;
    }
#pragma unroll
    for (int i = 0; i < 4; ++i)
        c0[i] = beta[ci * 16 + b0 + i] - bias[i] * g[i];

    const size_t fidx =
        ((size_t)(chunk * 64 + (wv >> 1)) * 1024 + ci * 32 + (wv & 1) * 16) * 16
        + lane * 4;
    const float* p = x + fidx;
    float* q = out + fidx;

    for (int it = 0; it < 32; ++it, p += 32768, q += 32768) {
        const float4 f = *reinterpret_cast<const float4*>(p);
        const float ow[4] = {f.x, f.y, f.z, f.w};

        float v[16];
#pragma unroll
        for (int j = 0; j < 4; ++j) {
            v[0  + j] = quad_bcast<0x00>(ow[j]);
            v[4  + j] = quad_bcast<0x55>(ow[j]);
            v[8  + j] = quad_bcast<0xAA>(ow[j]);
            v[12 + j] = quad_bcast<0xFF>(ow[j]);
        }

        float oacc[4] = {c0[0], c0[1], c0[2], c0[3]};
#pragma unroll
        for (int a = 0; a < 16; ++a) {
#pragma unroll
            for (int i = 0; i < 4; ++i) oacc[i] += v[a] * wg[a][i];
        }

        f32x4 o;
        o.x = oacc[0]; o.y = oacc[1]; o.z = oacc[2]; o.w = oacc[3];
        __builtin_nontemporal_store(o, reinterpret_cast<f32x4*>(q));
    }
}

// ---------------------------------------------------------------------------
extern "C" void kernel_launch(void* const* d_in, const int* in_sizes, int n_in,
                              void* d_out, int out_size, void* d_ws, size_t ws_size,
                              hipStream_t stream) {
    const float* x     = (const float*)d_in[0];
    const float* gamma = (const float*)d_in[1];
    const float* beta  = (const float*)d_in[2];
    float* out = (float*)d_out;
    float* ws  = (float*)d_ws;

    k_stats<<<dim3(1024), dim3(256), 0, stream>>>(x, ws);
    k_ns<<<dim3(32), dim3(256), 0, stream>>>(ws);
    k_apply<<<dim3(1024), dim3(256), 0, stream>>>(x, gamma, beta, ws, out);
}